// Round 4
// baseline (408.589 us; speedup 1.0000x reference)
//
#include <hip/hip_runtime.h>
#include <hip/hip_cooperative_groups.h>

namespace cg = cooperative_groups;

#define N_NODES 10000
#define N_EDGES 160000
#define NC 8
#define PAD 64          // per-node in-edge slot capacity; Poisson(16) => P(deg>64)~1e-17
#define LN_EPS 1e-5f

typedef _Float16 h4_t __attribute__((ext_vector_type(4)));
typedef _Float16 h8_t __attribute__((ext_vector_type(8)));

// Conflict-free LDS transpose swizzle for a 64x64 fp32 tile.
__device__ __forceinline__ int swz(int e, int b) {
  return e * 64 + ((((b >> 2) ^ ((e >> 2) & 15)) << 2) | (b & 3));
}

// One cooperative kernel, 4 phases separated by grid.sync().
// R3 lesson: without __launch_bounds__ the allocator capped VGPRs at 40 and
// spilled the edge phase's 16-gather pipeline to scratch (VALUBusy 3.7%,
// HBM 5%). (256, 4) = min 4 waves/EU -> VGPR cap 128 -> no spill, 16 waves/CU.
__global__ void __launch_bounds__(256, 4) fused_kernel(
    const float* __restrict__ x, const float* __restrict__ w1,
    const float* __restrict__ b1, const float* __restrict__ gamma,
    const float* __restrict__ beta, const float* __restrict__ w3,
    const float* __restrict__ b3, const int* __restrict__ esrc,
    const int* __restrict__ edst, float* __restrict__ out,
    _Float16* __restrict__ xT_d, _Float16* __restrict__ w1_h,
    _Float16* __restrict__ v, int* __restrict__ cur_dst) {
  cg::grid_group grid = cg::this_grid();
  __shared__ float tile[64 * 64];
  __shared__ int pP[64];
  const int t = threadIdx.x;
  const int nb = gridDim.x;

  // ---------------- phase 0: zero cur_dst ----------------
  for (int i = blockIdx.x * 256 + t; i < N_NODES; i += nb * 256) cur_dst[i] = 0;
  grid.sync();

  // ---------------- phase 1: prep ----------------
  {
    const int u = t & 15;
    const int row = t >> 4;               // 0..15
    for (int tl = blockIdx.x; tl < N_EDGES / 64; tl += nb) {
      const int e0 = tl * 64;
      if (t < 64) {
        const int e = e0 + t;
        const int n = edst[e];
        int r = atomicAdd(&cur_dst[n], 1);
        if (r >= PAD) r = PAD - 1;        // unreachable; memory-safety clamp
        const int p = (n << 6) + r;
        pP[t] = p;
        const float4* wp1 = (const float4*)(w1 + (size_t)e * NC);
        const float4 wa = wp1[0], wb = wp1[1];
        h8_t hw;
        hw[0] = (_Float16)wa.x; hw[1] = (_Float16)wa.y;
        hw[2] = (_Float16)wa.z; hw[3] = (_Float16)wa.w;
        hw[4] = (_Float16)wb.x; hw[5] = (_Float16)wb.y;
        hw[6] = (_Float16)wb.z; hw[7] = (_Float16)wb.w;
        *(h8_t*)&w1_h[(size_t)p * NC] = hw;
      }
#pragma unroll
      for (int j = 0; j < 4; ++j) {       // read x rows (b), float4 over e
        const int b = j * 16 + row;
        const float4 xv = *(const float4*)&x[(size_t)b * N_EDGES + e0 + 4 * u];
        tile[swz(4 * u + 0, b)] = xv.x;
        tile[swz(4 * u + 1, b)] = xv.y;
        tile[swz(4 * u + 2, b)] = xv.z;
        tile[swz(4 * u + 3, b)] = xv.w;
      }
      __syncthreads();
#pragma unroll
      for (int j = 0; j < 4; ++j) {       // write sorted fp16 row: half4 over b
        const int r = j * 16 + row;
        const float4 vv =
            *(const float4*)&tile[r * 64 + ((u ^ ((r >> 2) & 15)) << 2)];
        h4_t hv;
        hv[0] = (_Float16)vv.x; hv[1] = (_Float16)vv.y;
        hv[2] = (_Float16)vv.z; hv[3] = (_Float16)vv.w;
        *(h4_t*)&xT_d[(size_t)pP[r] * 64 + 4 * u] = hv;
      }
      __syncthreads();                    // tile/pP reuse next iteration
    }
  }
  grid.sync();

  // ---------------- phase 2: node ----------------
  {
    const int wid = t >> 6;
    const int b = t & 63;
    for (int g = blockIdx.x; g < N_NODES / 4; g += nb) {
      const int n = g * 4 + wid;

      float a[NC];
#pragma unroll
      for (int c = 0; c < NC; ++c) a[c] = 0.f;

      const int s0 = n << 6;
      const int s1 = s0 + cur_dst[n];
      int i = s0;
      for (; i + 4 <= s1; i += 4) {
        float xe[4];
#pragma unroll
        for (int k = 0; k < 4; ++k) xe[k] = (float)xT_d[(size_t)(i + k) * 64 + b];
        h8_t wl[4];
#pragma unroll
        for (int k = 0; k < 4; ++k) wl[k] = *(const h8_t*)&w1_h[(size_t)(i + k) * NC];
#pragma unroll
        for (int k = 0; k < 4; ++k) {
#pragma unroll
          for (int c = 0; c < NC; ++c) a[c] += xe[k] * (float)wl[k][c];
        }
      }
      for (; i < s1; ++i) {
        const float xe = (float)xT_d[(size_t)i * 64 + b];
        const h8_t wl = *(const h8_t*)&w1_h[(size_t)i * NC];
#pragma unroll
        for (int c = 0; c < NC; ++c) a[c] += xe * (float)wl[c];
      }

      const float4* b1p = (const float4*)(b1 + (size_t)n * NC);
      const float4 b1a = b1p[0], b1b = b1p[1];
      a[0] += b1a.x; a[1] += b1a.y; a[2] += b1a.z; a[3] += b1a.w;
      a[4] += b1b.x; a[5] += b1b.y; a[6] += b1b.z; a[7] += b1b.w;

      float mu = 0.f;
#pragma unroll
      for (int c = 0; c < NC; ++c) mu += a[c];
      mu *= 0.125f;
      float var = 0.f;
#pragma unroll
      for (int c = 0; c < NC; ++c) { a[c] -= mu; var += a[c] * a[c]; }
      var *= 0.125f;
      const float rs = rsqrtf(var + LN_EPS);

      const float4* gp = (const float4*)(gamma + (size_t)n * NC);
      const float4 ga = gp[0], gb = gp[1];
      const float4* bp = (const float4*)(beta + (size_t)n * NC);
      const float4 ba = bp[0], bb = bp[1];
      float w[NC];
      w[0] = a[0] * rs * ga.x + ba.x;  w[1] = a[1] * rs * ga.y + ba.y;
      w[2] = a[2] * rs * ga.z + ba.z;  w[3] = a[3] * rs * ga.w + ba.w;
      w[4] = a[4] * rs * gb.x + bb.x;  w[5] = a[5] * rs * gb.y + bb.y;
      w[6] = a[6] * rs * gb.z + bb.z;  w[7] = a[7] * rs * gb.w + bb.w;
#pragma unroll
      for (int c = 0; c < NC; ++c) w[c] = w[c] > 0.f ? w[c] : expm1f(w[c]);

      h8_t hv;
#pragma unroll
      for (int c = 0; c < NC; ++c) hv[c] = (_Float16)w[c];
      *(h8_t*)&v[(size_t)n * 512 + b * NC] = hv;  // wave writes 1KB contiguous
    }
  }
  grid.sync();

  // ---------------- phase 3: edge ----------------
  {
    const int w = t >> 6;                 // wave 0..3 -> edges w*16..w*16+15
    const int b = t & 63;
    const int u = t & 15;
    const int row = t >> 4;               // 0..15
    for (int tl = blockIdx.x; tl < N_EDGES / 64; tl += nb) {
      const int e0 = tl * 64;

      int sidx = 0;
      if (b < 16) sidx = esrc[e0 + w * 16 + b];

      // issue all 16 v-row gathers (16B/lane each) before any dependent use
      h8_t hv[16];
#pragma unroll
      for (int r = 0; r < 16; ++r) {
        const int s = __shfl(sidx, r, 64);
        hv[r] = *(const h8_t*)&v[(size_t)s * 512 + b * NC];
      }
      // prefetch independent final-phase operands while gathers are in flight
      const float4 bb = *(const float4*)&b3[e0 + 4 * u];
      float4 xb[4];
#pragma unroll
      for (int j = 0; j < 4; ++j) {
        const int bo = j * 16 + row;
        xb[j] = *(const float4*)&x[(size_t)bo * N_EDGES + e0 + 4 * u];
      }

#pragma unroll
      for (int r = 0; r < 16; ++r) {
        const float4* wp = (const float4*)(w3 + (size_t)(e0 + w * 16 + r) * NC);
        const float4 wa = wp[0], wb = wp[1];
        const float dot =
            (float)hv[r][0] * wa.x + (float)hv[r][1] * wa.y +
            (float)hv[r][2] * wa.z + (float)hv[r][3] * wa.w +
            (float)hv[r][4] * wb.x + (float)hv[r][5] * wb.y +
            (float)hv[r][6] * wb.z + (float)hv[r][7] * wb.w;
        tile[swz(w * 16 + r, b)] = dot;
      }
      __syncthreads();

#pragma unroll
      for (int j = 0; j < 4; ++j) {
        const int bo = j * 16 + row;
        const float o0 = tile[swz(4 * u + 0, bo)];
        const float o1 = tile[swz(4 * u + 1, bo)];
        const float o2 = tile[swz(4 * u + 2, bo)];
        const float o3 = tile[swz(4 * u + 3, bo)];
        float4 o;
        o.x = o0 + bb.x + xb[j].x;  o.y = o1 + bb.y + xb[j].y;
        o.z = o2 + bb.z + xb[j].z;  o.w = o3 + bb.w + xb[j].w;
        *(float4*)&out[(size_t)bo * N_EDGES + e0 + 4 * u] = o;
      }
      __syncthreads();                    // tile reuse next iteration
    }
  }
}

extern "C" void kernel_launch(void* const* d_in, const int* in_sizes, int n_in,
                              void* d_out, int out_size, void* d_ws, size_t ws_size,
                              hipStream_t stream) {
  const float* x     = (const float*)d_in[0];
  const float* w1    = (const float*)d_in[1];
  const float* b1    = (const float*)d_in[2];
  const float* gamma = (const float*)d_in[3];
  const float* beta  = (const float*)d_in[4];
  const float* w3    = (const float*)d_in[5];
  const float* b3    = (const float*)d_in[6];
  const int* esrc    = (const int*)d_in[7];
  const int* edst    = (const int*)d_in[8];
  float* out = (float*)d_out;

  char* ws = (char*)d_ws;
  size_t off = 0;
  auto alloc = [&](size_t bytes) -> void* {
    void* p = ws + off;
    off += (bytes + 255) & ~(size_t)255;
    return p;
  };
  _Float16* xT_d = (_Float16*)alloc((size_t)N_NODES * PAD * 64 * 2);  // 81.92 MB
  _Float16* w1_h = (_Float16*)alloc((size_t)N_NODES * PAD * NC * 2);  // 10.24 MB
  _Float16* v    = (_Float16*)alloc((size_t)N_NODES * 512 * 2);       // 10.24 MB
  int* cur_dst   = (int*)alloc((size_t)N_NODES * 4);

  // Cooperative grid: size from the occupancy API so all blocks are
  // guaranteed co-resident under the (256,4) bound. Clamped to max useful
  // work (2500 tiles).
  static int grid_blocks = 0;
  if (grid_blocks == 0) {
    int bpc = 0;
    if (hipOccupancyMaxActiveBlocksPerMultiprocessor(&bpc, fused_kernel, 256, 0)
            != hipSuccess || bpc < 1)
      bpc = 2;
    grid_blocks = bpc * 256;
    if (grid_blocks > 2500) grid_blocks = 2500;
  }

  void* kargs[] = {(void*)&x,    (void*)&w1,   (void*)&b1,  (void*)&gamma,
                   (void*)&beta, (void*)&w3,   (void*)&b3,  (void*)&esrc,
                   (void*)&edst, (void*)&out,  (void*)&xT_d, (void*)&w1_h,
                   (void*)&v,    (void*)&cur_dst};
  hipLaunchCooperativeKernel((const void*)fused_kernel, dim3(grid_blocks),
                             dim3(256), kargs, 0, stream);
}

// Round 5
// 347.925 us; speedup vs baseline: 1.1744x; 1.1744x over previous
//
#include <hip/hip_runtime.h>
#include <hip/hip_cooperative_groups.h>

namespace cg = cooperative_groups;

#define N_NODES 10000
#define N_EDGES 160000
#define NC 8
#define PAD 64          // per-node in-edge slot capacity; Poisson(16) => P(deg>64)~1e-17
#define LN_EPS 1e-5f

typedef _Float16 h4_t __attribute__((ext_vector_type(4)));
typedef _Float16 h8_t __attribute__((ext_vector_type(8)));

// Conflict-free LDS transpose swizzle for a 64x64 fp32 tile.
__device__ __forceinline__ int swz(int e, int b) {
  return e * 64 + ((((b >> 2) ^ ((e >> 2) & 15)) << 2) | (b & 3));
}

// One cooperative kernel, 4 phases separated by grid.sync().
// R3/R4 lesson: VGPR_Count=40 both rounds — launch_bounds(256,4) only sets the
// occupancy FLOOR; the allocator still targeted ~12 waves/EU and spilled every
// phase's load pipeline to scratch (VALUBusy 3.7%, 430 GB/s latency-bound).
// amdgpu_waves_per_eu(4,4) pins the occupancy TARGET to 4 waves/EU ->
// 128-VGPR budget -> the 16-gather / 4-deep pipelines stay in registers.
__global__ void __launch_bounds__(256)
__attribute__((amdgpu_waves_per_eu(4, 4))) fused_kernel(
    const float* __restrict__ x, const float* __restrict__ w1,
    const float* __restrict__ b1, const float* __restrict__ gamma,
    const float* __restrict__ beta, const float* __restrict__ w3,
    const float* __restrict__ b3, const int* __restrict__ esrc,
    const int* __restrict__ edst, float* __restrict__ out,
    _Float16* __restrict__ xT_d, _Float16* __restrict__ w1_h,
    _Float16* __restrict__ v, int* __restrict__ cur_dst) {
  cg::grid_group grid = cg::this_grid();
  __shared__ float tile[64 * 64];
  __shared__ int pP[64];
  const int t = threadIdx.x;
  const int nb = gridDim.x;

  // ---------------- phase 0: zero cur_dst ----------------
  for (int i = blockIdx.x * 256 + t; i < N_NODES; i += nb * 256) cur_dst[i] = 0;
  grid.sync();

  // ---------------- phase 1: prep ----------------
  {
    const int u = t & 15;
    const int row = t >> 4;               // 0..15
    for (int tl = blockIdx.x; tl < N_EDGES / 64; tl += nb) {
      const int e0 = tl * 64;
      if (t < 64) {
        const int e = e0 + t;
        const int n = edst[e];
        int r = atomicAdd(&cur_dst[n], 1);
        if (r >= PAD) r = PAD - 1;        // unreachable; memory-safety clamp
        const int p = (n << 6) + r;
        pP[t] = p;
        const float4* wp1 = (const float4*)(w1 + (size_t)e * NC);
        const float4 wa = wp1[0], wb = wp1[1];
        h8_t hw;
        hw[0] = (_Float16)wa.x; hw[1] = (_Float16)wa.y;
        hw[2] = (_Float16)wa.z; hw[3] = (_Float16)wa.w;
        hw[4] = (_Float16)wb.x; hw[5] = (_Float16)wb.y;
        hw[6] = (_Float16)wb.z; hw[7] = (_Float16)wb.w;
        *(h8_t*)&w1_h[(size_t)p * NC] = hw;
      }
#pragma unroll
      for (int j = 0; j < 4; ++j) {       // read x rows (b), float4 over e
        const int b = j * 16 + row;
        const float4 xv = *(const float4*)&x[(size_t)b * N_EDGES + e0 + 4 * u];
        tile[swz(4 * u + 0, b)] = xv.x;
        tile[swz(4 * u + 1, b)] = xv.y;
        tile[swz(4 * u + 2, b)] = xv.z;
        tile[swz(4 * u + 3, b)] = xv.w;
      }
      __syncthreads();
#pragma unroll
      for (int j = 0; j < 4; ++j) {       // write sorted fp16 row: half4 over b
        const int r = j * 16 + row;
        const float4 vv =
            *(const float4*)&tile[r * 64 + ((u ^ ((r >> 2) & 15)) << 2)];
        h4_t hv;
        hv[0] = (_Float16)vv.x; hv[1] = (_Float16)vv.y;
        hv[2] = (_Float16)vv.z; hv[3] = (_Float16)vv.w;
        *(h4_t*)&xT_d[(size_t)pP[r] * 64 + 4 * u] = hv;
      }
      __syncthreads();                    // tile/pP reuse next iteration
    }
  }
  grid.sync();

  // ---------------- phase 2: node ----------------
  {
    const int wid = t >> 6;
    const int b = t & 63;
    for (int g = blockIdx.x; g < N_NODES / 4; g += nb) {
      const int n = g * 4 + wid;

      float a[NC];
#pragma unroll
      for (int c = 0; c < NC; ++c) a[c] = 0.f;

      const int s0 = n << 6;
      const int s1 = s0 + cur_dst[n];
      int i = s0;
      for (; i + 4 <= s1; i += 4) {
        float xe[4];
#pragma unroll
        for (int k = 0; k < 4; ++k) xe[k] = (float)xT_d[(size_t)(i + k) * 64 + b];
        h8_t wl[4];
#pragma unroll
        for (int k = 0; k < 4; ++k) wl[k] = *(const h8_t*)&w1_h[(size_t)(i + k) * NC];
#pragma unroll
        for (int k = 0; k < 4; ++k) {
#pragma unroll
          for (int c = 0; c < NC; ++c) a[c] += xe[k] * (float)wl[k][c];
        }
      }
      for (; i < s1; ++i) {
        const float xe = (float)xT_d[(size_t)i * 64 + b];
        const h8_t wl = *(const h8_t*)&w1_h[(size_t)i * NC];
#pragma unroll
        for (int c = 0; c < NC; ++c) a[c] += xe * (float)wl[c];
      }

      const float4* b1p = (const float4*)(b1 + (size_t)n * NC);
      const float4 b1a = b1p[0], b1b = b1p[1];
      a[0] += b1a.x; a[1] += b1a.y; a[2] += b1a.z; a[3] += b1a.w;
      a[4] += b1b.x; a[5] += b1b.y; a[6] += b1b.z; a[7] += b1b.w;

      float mu = 0.f;
#pragma unroll
      for (int c = 0; c < NC; ++c) mu += a[c];
      mu *= 0.125f;
      float var = 0.f;
#pragma unroll
      for (int c = 0; c < NC; ++c) { a[c] -= mu; var += a[c] * a[c]; }
      var *= 0.125f;
      const float rs = rsqrtf(var + LN_EPS);

      const float4* gp = (const float4*)(gamma + (size_t)n * NC);
      const float4 ga = gp[0], gb = gp[1];
      const float4* bp = (const float4*)(beta + (size_t)n * NC);
      const float4 ba = bp[0], bb = bp[1];
      float w[NC];
      w[0] = a[0] * rs * ga.x + ba.x;  w[1] = a[1] * rs * ga.y + ba.y;
      w[2] = a[2] * rs * ga.z + ba.z;  w[3] = a[3] * rs * ga.w + ba.w;
      w[4] = a[4] * rs * gb.x + bb.x;  w[5] = a[5] * rs * gb.y + bb.y;
      w[6] = a[6] * rs * gb.z + bb.z;  w[7] = a[7] * rs * gb.w + bb.w;
#pragma unroll
      for (int c = 0; c < NC; ++c) w[c] = w[c] > 0.f ? w[c] : expm1f(w[c]);

      h8_t hv;
#pragma unroll
      for (int c = 0; c < NC; ++c) hv[c] = (_Float16)w[c];
      *(h8_t*)&v[(size_t)n * 512 + b * NC] = hv;  // wave writes 1KB contiguous
    }
  }
  grid.sync();

  // ---------------- phase 3: edge ----------------
  {
    const int w = t >> 6;                 // wave 0..3 -> edges w*16..w*16+15
    const int b = t & 63;
    const int u = t & 15;
    const int row = t >> 4;               // 0..15
    for (int tl = blockIdx.x; tl < N_EDGES / 64; tl += nb) {
      const int e0 = tl * 64;

      int sidx = 0;
      if (b < 16) sidx = esrc[e0 + w * 16 + b];

      // issue all 16 v-row gathers (16B/lane each) before any dependent use
      h8_t hv[16];
#pragma unroll
      for (int r = 0; r < 16; ++r) {
        const int s = __shfl(sidx, r, 64);
        hv[r] = *(const h8_t*)&v[(size_t)s * 512 + b * NC];
      }
      // prefetch independent final-phase operands while gathers are in flight
      const float4 bb = *(const float4*)&b3[e0 + 4 * u];
      float4 xb[4];
#pragma unroll
      for (int j = 0; j < 4; ++j) {
        const int bo = j * 16 + row;
        xb[j] = *(const float4*)&x[(size_t)bo * N_EDGES + e0 + 4 * u];
      }

#pragma unroll
      for (int r = 0; r < 16; ++r) {
        const float4* wp = (const float4*)(w3 + (size_t)(e0 + w * 16 + r) * NC);
        const float4 wa = wp[0], wb = wp[1];
        const float dot =
            (float)hv[r][0] * wa.x + (float)hv[r][1] * wa.y +
            (float)hv[r][2] * wa.z + (float)hv[r][3] * wa.w +
            (float)hv[r][4] * wb.x + (float)hv[r][5] * wb.y +
            (float)hv[r][6] * wb.z + (float)hv[r][7] * wb.w;
        tile[swz(w * 16 + r, b)] = dot;
      }
      __syncthreads();

#pragma unroll
      for (int j = 0; j < 4; ++j) {
        const int bo = j * 16 + row;
        const float o0 = tile[swz(4 * u + 0, bo)];
        const float o1 = tile[swz(4 * u + 1, bo)];
        const float o2 = tile[swz(4 * u + 2, bo)];
        const float o3 = tile[swz(4 * u + 3, bo)];
        float4 o;
        o.x = o0 + bb.x + xb[j].x;  o.y = o1 + bb.y + xb[j].y;
        o.z = o2 + bb.z + xb[j].z;  o.w = o3 + bb.w + xb[j].w;
        *(float4*)&out[(size_t)bo * N_EDGES + e0 + 4 * u] = o;
      }
      __syncthreads();                    // tile reuse next iteration
    }
  }
}

extern "C" void kernel_launch(void* const* d_in, const int* in_sizes, int n_in,
                              void* d_out, int out_size, void* d_ws, size_t ws_size,
                              hipStream_t stream) {
  const float* x     = (const float*)d_in[0];
  const float* w1    = (const float*)d_in[1];
  const float* b1    = (const float*)d_in[2];
  const float* gamma = (const float*)d_in[3];
  const float* beta  = (const float*)d_in[4];
  const float* w3    = (const float*)d_in[5];
  const float* b3    = (const float*)d_in[6];
  const int* esrc    = (const int*)d_in[7];
  const int* edst    = (const int*)d_in[8];
  float* out = (float*)d_out;

  char* ws = (char*)d_ws;
  size_t off = 0;
  auto alloc = [&](size_t bytes) -> void* {
    void* p = ws + off;
    off += (bytes + 255) & ~(size_t)255;
    return p;
  };
  _Float16* xT_d = (_Float16*)alloc((size_t)N_NODES * PAD * 64 * 2);  // 81.92 MB
  _Float16* w1_h = (_Float16*)alloc((size_t)N_NODES * PAD * NC * 2);  // 10.24 MB
  _Float16* v    = (_Float16*)alloc((size_t)N_NODES * 512 * 2);       // 10.24 MB
  int* cur_dst   = (int*)alloc((size_t)N_NODES * 4);

  // Cooperative grid: size from the occupancy API so all blocks are
  // guaranteed co-resident under the pinned 4-waves/EU occupancy.
  static int grid_blocks = 0;
  if (grid_blocks == 0) {
    int bpc = 0;
    if (hipOccupancyMaxActiveBlocksPerMultiprocessor(&bpc, fused_kernel, 256, 0)
            != hipSuccess || bpc < 1)
      bpc = 2;
    grid_blocks = bpc * 256;
    if (grid_blocks > 2500) grid_blocks = 2500;
  }

  void* kargs[] = {(void*)&x,    (void*)&w1,   (void*)&b1,  (void*)&gamma,
                   (void*)&beta, (void*)&w3,   (void*)&b3,  (void*)&esrc,
                   (void*)&edst, (void*)&out,  (void*)&xT_d, (void*)&w1_h,
                   (void*)&v,    (void*)&cur_dst};
  hipLaunchCooperativeKernel((const void*)fused_kernel, dim3(grid_blocks),
                             dim3(256), kargs, 0, stream);
}

// Round 6
// 169.328 us; speedup vs baseline: 2.4130x; 2.0547x over previous
//
#include <hip/hip_runtime.h>

#define N_NODES 10000
#define N_EDGES 160000
#define NC 8
#define PAD 64          // per-node in-edge slot capacity; Poisson(16) => P(deg>64)~1e-17
#define LN_EPS 1e-5f

typedef _Float16 h4_t __attribute__((ext_vector_type(4)));
typedef _Float16 h8_t __attribute__((ext_vector_type(8)));

// Conflict-free LDS transpose swizzle for a 64x64 fp32 tile.
__device__ __forceinline__ int swz(int e, int b) {
  return e * 64 + ((((b >> 2) ^ ((e >> 2) & 15)) << 2) | (b & 3));
}

// ---------------- K1: transpose x -> xT[E][64] (fp16, coalesced) + CSR ids ---
// R5 lesson: don't scatter DATA (144 B/edge), scatter IDS (4 B/edge).
//   xT[e][b]            = (fp16)x[b][e]   (fully coalesced 128-B row writes)
//   ein[dst*64 + rank]  = e               (4-B scatter; rank via atomic)
// After this kernel cur_dst[n] == in-degree(n).
__global__ void __launch_bounds__(256) transpose_kernel(
    const float* __restrict__ x, const int* __restrict__ edst,
    int* __restrict__ cur_dst, _Float16* __restrict__ xT,
    int* __restrict__ ein) {
  __shared__ float tile[64 * 64];
  const int e0 = blockIdx.x * 64;
  const int t = threadIdx.x;

  if (t < 64) {
    const int e = e0 + t;
    const int n = edst[e];
    const int r = atomicAdd(&cur_dst[n], 1);
    if (r < PAD) ein[(n << 6) + r] = e;   // r>=PAD unreachable (safety skip)
  }

  const int u = t & 15;
  const int row = t >> 4;                 // 0..15
#pragma unroll
  for (int j = 0; j < 4; ++j) {           // read x rows (b), float4 over e
    const int b = j * 16 + row;
    const float4 xv = *(const float4*)&x[(size_t)b * N_EDGES + e0 + 4 * u];
    tile[swz(4 * u + 0, b)] = xv.x;
    tile[swz(4 * u + 1, b)] = xv.y;
    tile[swz(4 * u + 2, b)] = xv.z;
    tile[swz(4 * u + 3, b)] = xv.w;
  }
  __syncthreads();
#pragma unroll
  for (int j = 0; j < 4; ++j) {           // write xT row e0+r: half4 over b
    const int r = j * 16 + row;
    const float4 vv = *(const float4*)&tile[r * 64 + ((u ^ ((r >> 2) & 15)) << 2)];
    h4_t hv;
    hv[0] = (_Float16)vv.x; hv[1] = (_Float16)vv.y;
    hv[2] = (_Float16)vv.z; hv[3] = (_Float16)vv.w;
    *(h4_t*)&xT[(size_t)(e0 + r) * 64 + 4 * u] = hv;
  }
}

// ---------------- K2: segment-sum (CSR gather) + LN + ELU -> v[n][b][c] ------
// 4 nodes/block, lane = b. Per edge: ein id (wave-uniform -> scalar load),
// xT row gather (128 B contiguous, wave-uniform base + 2*b), w1 row read
// (wave-uniform -> scalar fp32 loads; no fp16 repack, better numerics).
__global__ void __launch_bounds__(256) node_kernel(
    const _Float16* __restrict__ xT, const int* __restrict__ ein,
    const float* __restrict__ w1, const float* __restrict__ b1,
    const float* __restrict__ gamma, const float* __restrict__ beta,
    const int* __restrict__ cur_dst, _Float16* __restrict__ v) {
  const int n = blockIdx.x * 4 + (threadIdx.x >> 6);
  const int b = threadIdx.x & 63;

  float a[NC];
#pragma unroll
  for (int c = 0; c < NC; ++c) a[c] = 0.f;

  const int s0 = n << 6;
  const int deg = min(cur_dst[n], PAD);
  const int s1 = s0 + deg;
  int i = s0;
  for (; i + 4 <= s1; i += 4) {
    int e[4];
#pragma unroll
    for (int k = 0; k < 4; ++k) e[k] = ein[i + k];
    float xe[4];
#pragma unroll
    for (int k = 0; k < 4; ++k) xe[k] = (float)xT[(size_t)e[k] * 64 + b];
    float4 wa[4], wb[4];
#pragma unroll
    for (int k = 0; k < 4; ++k) {
      const float4* wp = (const float4*)(w1 + (size_t)e[k] * NC);
      wa[k] = wp[0]; wb[k] = wp[1];
    }
#pragma unroll
    for (int k = 0; k < 4; ++k) {
      a[0] += xe[k] * wa[k].x;  a[1] += xe[k] * wa[k].y;
      a[2] += xe[k] * wa[k].z;  a[3] += xe[k] * wa[k].w;
      a[4] += xe[k] * wb[k].x;  a[5] += xe[k] * wb[k].y;
      a[6] += xe[k] * wb[k].z;  a[7] += xe[k] * wb[k].w;
    }
  }
  for (; i < s1; ++i) {
    const int e = ein[i];
    const float xe = (float)xT[(size_t)e * 64 + b];
    const float4* wp = (const float4*)(w1 + (size_t)e * NC);
    const float4 wa = wp[0], wb = wp[1];
    a[0] += xe * wa.x;  a[1] += xe * wa.y;
    a[2] += xe * wa.z;  a[3] += xe * wa.w;
    a[4] += xe * wb.x;  a[5] += xe * wb.y;
    a[6] += xe * wb.z;  a[7] += xe * wb.w;
  }

  const float4* b1p = (const float4*)(b1 + (size_t)n * NC);
  const float4 b1a = b1p[0], b1b = b1p[1];
  a[0] += b1a.x; a[1] += b1a.y; a[2] += b1a.z; a[3] += b1a.w;
  a[4] += b1b.x; a[5] += b1b.y; a[6] += b1b.z; a[7] += b1b.w;

  float mu = 0.f;
#pragma unroll
  for (int c = 0; c < NC; ++c) mu += a[c];
  mu *= 0.125f;
  float var = 0.f;
#pragma unroll
  for (int c = 0; c < NC; ++c) { a[c] -= mu; var += a[c] * a[c]; }
  var *= 0.125f;
  const float rs = rsqrtf(var + LN_EPS);

  const float4* gp = (const float4*)(gamma + (size_t)n * NC);
  const float4 ga = gp[0], gb = gp[1];
  const float4* bp = (const float4*)(beta + (size_t)n * NC);
  const float4 ba = bp[0], bb = bp[1];
  float w[NC];
  w[0] = a[0] * rs * ga.x + ba.x;  w[1] = a[1] * rs * ga.y + ba.y;
  w[2] = a[2] * rs * ga.z + ba.z;  w[3] = a[3] * rs * ga.w + ba.w;
  w[4] = a[4] * rs * gb.x + bb.x;  w[5] = a[5] * rs * gb.y + bb.y;
  w[6] = a[6] * rs * gb.z + bb.z;  w[7] = a[7] * rs * gb.w + bb.w;
#pragma unroll
  for (int c = 0; c < NC; ++c) w[c] = w[c] > 0.f ? w[c] : expm1f(w[c]);

  h8_t hv;
#pragma unroll
  for (int c = 0; c < NC; ++c) hv[c] = (_Float16)w[c];
  *(h8_t*)&v[(size_t)n * 512 + b * NC] = hv;     // wave writes 1KB contiguous
}

// ---------------- K3: edge kernel — gather v[src], dot w3, +b3+x -> out ------
// 64 edges/block; 4 waves x 16 edges. All 16 v-row gathers issued before any
// use; x/b3 prefetched alongside. LDS transpose -> coalesced float4 out writes.
__global__ void __launch_bounds__(256) edge_kernel(
    const _Float16* __restrict__ v, const float* __restrict__ w3,
    const float* __restrict__ b3, const float* __restrict__ x,
    const int* __restrict__ esrc, float* __restrict__ out) {
  __shared__ float tile[64 * 64];
  const int e0 = blockIdx.x * 64;
  const int t = threadIdx.x;
  const int w = t >> 6;                   // wave 0..3 -> edges w*16..w*16+15
  const int b = t & 63;
  const int u = t & 15;
  const int row = t >> 4;                 // 0..15

  int sidx = 0;
  if (b < 16) sidx = esrc[e0 + w * 16 + b];

  // issue all 16 v-row gathers (16B/lane each) before any dependent use
  h8_t hv[16];
#pragma unroll
  for (int r = 0; r < 16; ++r) {
    const int s = __shfl(sidx, r, 64);
    hv[r] = *(const h8_t*)&v[(size_t)s * 512 + b * NC];
  }
  // prefetch the independent final-phase operands while gathers are in flight
  const float4 bb = *(const float4*)&b3[e0 + 4 * u];
  float4 xb[4];
#pragma unroll
  for (int j = 0; j < 4; ++j) {
    const int bo = j * 16 + row;
    xb[j] = *(const float4*)&x[(size_t)bo * N_EDGES + e0 + 4 * u];
  }

#pragma unroll
  for (int r = 0; r < 16; ++r) {
    const float4* wp = (const float4*)(w3 + (size_t)(e0 + w * 16 + r) * NC);
    const float4 wa = wp[0], wb = wp[1];
    const float dot =
        (float)hv[r][0] * wa.x + (float)hv[r][1] * wa.y +
        (float)hv[r][2] * wa.z + (float)hv[r][3] * wa.w +
        (float)hv[r][4] * wb.x + (float)hv[r][5] * wb.y +
        (float)hv[r][6] * wb.z + (float)hv[r][7] * wb.w;
    tile[swz(w * 16 + r, b)] = dot;
  }
  __syncthreads();

#pragma unroll
  for (int j = 0; j < 4; ++j) {
    const int bo = j * 16 + row;
    const float o0 = tile[swz(4 * u + 0, bo)];
    const float o1 = tile[swz(4 * u + 1, bo)];
    const float o2 = tile[swz(4 * u + 2, bo)];
    const float o3 = tile[swz(4 * u + 3, bo)];
    float4 o;
    o.x = o0 + bb.x + xb[j].x;  o.y = o1 + bb.y + xb[j].y;
    o.z = o2 + bb.z + xb[j].z;  o.w = o3 + bb.w + xb[j].w;
    *(float4*)&out[(size_t)bo * N_EDGES + e0 + 4 * u] = o;
  }
}

extern "C" void kernel_launch(void* const* d_in, const int* in_sizes, int n_in,
                              void* d_out, int out_size, void* d_ws, size_t ws_size,
                              hipStream_t stream) {
  const float* x     = (const float*)d_in[0];
  const float* w1    = (const float*)d_in[1];
  const float* b1    = (const float*)d_in[2];
  const float* gamma = (const float*)d_in[3];
  const float* beta  = (const float*)d_in[4];
  const float* w3    = (const float*)d_in[5];
  const float* b3    = (const float*)d_in[6];
  const int* esrc    = (const int*)d_in[7];
  const int* edst    = (const int*)d_in[8];
  float* out = (float*)d_out;

  char* ws = (char*)d_ws;
  size_t off = 0;
  auto alloc = [&](size_t bytes) -> void* {
    void* p = ws + off;
    off += (bytes + 255) & ~(size_t)255;
    return p;
  };
  _Float16* xT  = (_Float16*)alloc((size_t)N_EDGES * 64 * 2);        // 20.48 MB
  int* ein      = (int*)alloc((size_t)N_NODES * PAD * 4);            //  2.56 MB
  _Float16* v   = (_Float16*)alloc((size_t)N_NODES * 512 * 2);       // 10.24 MB
  int* cur_dst  = (int*)alloc((size_t)N_NODES * 4);

  hipMemsetAsync(cur_dst, 0, (size_t)N_NODES * 4, stream);

  transpose_kernel<<<N_EDGES / 64, 256, 0, stream>>>(x, edst, cur_dst, xT, ein);
  node_kernel<<<N_NODES / 4, 256, 0, stream>>>(xT, ein, w1, b1, gamma, beta,
                                               cur_dst, v);
  edge_kernel<<<N_EDGES / 64, 256, 0, stream>>>(v, w3, b3, x, esrc, out);
}